// Round 1
// 544.592 us; speedup vs baseline: 1.0069x; 1.0069x over previous
//
#include <hip/hip_runtime.h>
#include <math.h>

#define NN 10000
#define NE 320000
#define DD 64
#define TILE 128
#define NTILE 79            // ceil(10000/128)
#define NPAD (NTILE * TILE) // 10112
#define PADROWS (NPAD - NN) // 112
#define NPAIRS (NTILE * (NTILE + 1) / 2)  // 3160 upper-triangle tile pairs

typedef __bf16 bf16x8 __attribute__((ext_vector_type(8)));
typedef float f32x4 __attribute__((ext_vector_type(4)));

// workspace layout (byte offsets, 16B-aligned)
// cnt    int[10016]        @ 0
// fill   int[10016]        @ 40064
// rowptr int[10016]        @ 80128
// srcrow int[320000]       @ 120192
// dinv   float[10016]      @ 1400192
// h      float[640000]     @ 1440256
// zr1    bf16[NPAD*64]     @ 4000256   (1294336 B)
// zr2    bf16[NPAD*64]     @ 5294592   -> end 6588928 B
#define OFF_CNT    0
#define OFF_FILL   40064
#define OFF_ROWPTR 80128
#define OFF_SRC    120192
#define OFF_DINV   1400192
#define OFF_H      1440256
#define OFF_ZR1    4000256
#define OFF_ZR2    5294592

// ---------------------------------------------------------------------------
// zero cnt, fill; zero pad rows of zr1/zr2 (rows NN..NPAD)
__global__ void init_kernel(int* __restrict__ cnt, int* __restrict__ fill,
                            unsigned short* __restrict__ zr1,
                            unsigned short* __restrict__ zr2) {
    int tid = blockIdx.x * 256 + threadIdx.x;
    if (tid < NN) { cnt[tid] = 0; fill[tid] = 0; }
    if (tid < PADROWS * DD) {
        zr1[NN * DD + tid] = 0;
        zr2[NN * DD + tid] = 0;
    }
}

// ---------------------------------------------------------------------------
__global__ void count_kernel(const int* __restrict__ ei, int* __restrict__ cnt) {
    int e = blockIdx.x * 256 + threadIdx.x;
    if (e < NE) atomicAdd(&cnt[ei[NE + e]], 1);
}

__global__ void dinv_kernel(const int* __restrict__ cnt, float* __restrict__ dinv) {
    int i = blockIdx.x * 256 + threadIdx.x;
    if (i < NN) dinv[i] = rsqrtf((float)cnt[i] + 1.0f);  // +1 self loop
}

// ---------------------------------------------------------------------------
// single-block exclusive scan of cnt[NN] -> rowptr[NN+1]
__global__ __launch_bounds__(256) void scan_kernel(const int* __restrict__ cnt,
                                                   int* __restrict__ rowptr) {
    __shared__ int partial[256];
    const int t = threadIdx.x;
    const int base = t * 40;  // 256*40 = 10240 >= NN
    int s = 0;
#pragma unroll 4
    for (int i = 0; i < 40; i++) {
        int idx = base + i;
        if (idx < NN) s += cnt[idx];
    }
    partial[t] = s;
    __syncthreads();
    for (int off = 1; off < 256; off <<= 1) {
        int v = (t >= off) ? partial[t - off] : 0;
        __syncthreads();
        partial[t] += v;
        __syncthreads();
    }
    int run = (t == 0) ? 0 : partial[t - 1];
    for (int i = 0; i < 40; i++) {
        int idx = base + i;
        if (idx < NN) { rowptr[idx] = run; run += cnt[idx]; }
    }
    if (t == 255) rowptr[NN] = partial[255];
}

// ---------------------------------------------------------------------------
__global__ void fill_kernel(const int* __restrict__ ei,
                            const int* __restrict__ rowptr,
                            int* __restrict__ fill, int* __restrict__ srcrow) {
    int e = blockIdx.x * 256 + threadIdx.x;
    if (e >= NE) return;
    int c = ei[NE + e];
    int pos = rowptr[c] + atomicAdd(&fill[c], 1);
    srcrow[pos] = ei[e];
}

// ---------------------------------------------------------------------------
// h = z @ W   (4 rows per block, W staged in LDS)
__global__ __launch_bounds__(256) void h_kernel(const float* __restrict__ z,
                                                const float* __restrict__ W,
                                                float* __restrict__ h) {
    __shared__ float Ws[64 * 64];
    __shared__ float zs[4 * 64];
    const int tid = threadIdx.x;
    const int rbase = blockIdx.x * 4;
#pragma unroll
    for (int i = 0; i < 16; i++) Ws[i * 256 + tid] = W[i * 256 + tid];
    zs[tid] = z[rbase * DD + tid];
    __syncthreads();
    const int r = tid >> 6, d = tid & 63;
    float acc = 0.0f;
#pragma unroll
    for (int k = 0; k < 64; k++) acc = fmaf(zs[r * 64 + k], Ws[k * 64 + d], acc);
    h[(rbase + r) * DD + d] = acc;
}

// ---------------------------------------------------------------------------
// gather-aggregate: one wave per destination node, lane = feature dim.
// zr = relu(sum_in h[r]*dinv[r]*dinv[c] + h[c]*dinv[c]^2 + b); split to bf16 hi/lo
__global__ __launch_bounds__(256) void agg_kernel(const int* __restrict__ rowptr,
                                                  const int* __restrict__ srcrow,
                                                  const float* __restrict__ dinv,
                                                  const float* __restrict__ h,
                                                  const float* __restrict__ b,
                                                  __bf16* __restrict__ zr1,
                                                  __bf16* __restrict__ zr2) {
    const int lane = threadIdx.x & 63;
    const int n = blockIdx.x * 4 + (threadIdx.x >> 6);
    if (n >= NN) return;
    int s = __builtin_amdgcn_readfirstlane(rowptr[n]);
    int e = __builtin_amdgcn_readfirstlane(rowptr[n + 1]);
    const float dc = dinv[n];
    float acc = 0.0f;
    int i = s;
    // 2-deep manual pipeline to overlap srcrow->h latency
    for (; i + 1 < e; i += 2) {
        int r0 = __builtin_amdgcn_readfirstlane(srcrow[i]);
        int r1 = __builtin_amdgcn_readfirstlane(srcrow[i + 1]);
        float n0 = dinv[r0] * dc, n1 = dinv[r1] * dc;
        float h0 = h[r0 * DD + lane], h1 = h[r1 * DD + lane];
        acc = fmaf(h0, n0, acc);
        acc = fmaf(h1, n1, acc);
    }
    for (; i < e; i++) {
        int r = __builtin_amdgcn_readfirstlane(srcrow[i]);
        acc = fmaf(h[r * DD + lane], dinv[r] * dc, acc);
    }
    acc = fmaf(h[n * DD + lane], dc * dc, acc) + b[lane];
    acc = acc > 0.0f ? acc : 0.0f;
    __bf16 hi = (__bf16)acc;
    float rem = acc - (float)hi;
    zr1[n * DD + lane] = hi;
    zr2[n * DD + lane] = (__bf16)rem;
}

// ---------------------------------------------------------------------------
// C = zr @ zr^T via bf16x3-split MFMA. C is SYMMETRIC: compute only upper-
// triangle 128x128 tiles (bi <= bj), store in place + transposed mirror.
// 4 waves 2x2 per block, each wave 64x64 = 4x4 tiles of 16x16, K=64 in 2
// steps of 32 (mfma_f32_16x16x32_bf16).
// Mirror store exploits C/D layout (col=lane&15, row=(lane>>4)*4+reg): the 4
// regs are contiguous along the transposed row -> global_store_dwordx4.
// NN % 4 == 0 so the x4 store needs only a col0 < NN guard; 40000 % 16 == 0
// keeps it 16B-aligned.
__global__ __launch_bounds__(256) void gemm_kernel(const __bf16* __restrict__ z1,
                                                   const __bf16* __restrict__ z2,
                                                   float* __restrict__ C) {
    // triangular decode: block t -> (bi, bj), bi <= bj
    const int t = blockIdx.x;
    const float ff = (float)(2 * NTILE + 1);
    int bi = (int)((ff - sqrtf(ff * ff - 8.0f * (float)t)) * 0.5f);
    while ((bi + 1) * NTILE - ((bi + 1) * bi) / 2 <= t) bi++;
    while (bi * NTILE - (bi * (bi - 1)) / 2 > t) bi--;
    const int bj = bi + (t - (bi * NTILE - (bi * (bi - 1)) / 2));

    const int tid = threadIdx.x;
    const int lane = tid & 63;
    const int w = tid >> 6;
    const int wr = w >> 1, wc = w & 1;
    const int m16 = lane & 15;
    const int kq = lane >> 4;
    const int rbase = bi * TILE + wr * 64;
    const int cbase = bj * TILE + wc * 64;

    f32x4 acc[4][4] = {};

    for (int kk = 0; kk < 2; kk++) {
        const int ko = kk * 32 + kq * 8;
        bf16x8 a1[4], a2[4], b1[4], b2[4];
#pragma unroll
        for (int tt = 0; tt < 4; tt++) {
            const int ar = rbase + tt * 16 + m16;
            const int br = cbase + tt * 16 + m16;
            a1[tt] = *(const bf16x8*)&z1[ar * DD + ko];
            a2[tt] = *(const bf16x8*)&z2[ar * DD + ko];
            b1[tt] = *(const bf16x8*)&z1[br * DD + ko];
            b2[tt] = *(const bf16x8*)&z2[br * DD + ko];
        }
#pragma unroll
        for (int mt = 0; mt < 4; mt++)
#pragma unroll
            for (int nt = 0; nt < 4; nt++) {
                acc[mt][nt] = __builtin_amdgcn_mfma_f32_16x16x32_bf16(a2[mt], b1[nt], acc[mt][nt], 0, 0, 0);
                acc[mt][nt] = __builtin_amdgcn_mfma_f32_16x16x32_bf16(a1[mt], b2[nt], acc[mt][nt], 0, 0, 0);
                acc[mt][nt] = __builtin_amdgcn_mfma_f32_16x16x32_bf16(a1[mt], b1[nt], acc[mt][nt], 0, 0, 0);
            }
    }

    // in-place store: C/D layout col = lane&15, row = (lane>>4)*4 + reg
#pragma unroll
    for (int mt = 0; mt < 4; mt++) {
        const int row0 = rbase + mt * 16 + kq * 4;
#pragma unroll
        for (int nt = 0; nt < 4; nt++) {
            const int col = cbase + nt * 16 + m16;
            if (col < NN) {
#pragma unroll
                for (int r = 0; r < 4; r++) {
                    const int row = row0 + r;
                    if (row < NN) C[(size_t)row * NN + col] = acc[mt][nt][r];
                }
            }
        }
    }

    // mirror store (transposed), off-diagonal tiles only:
    // C[col][row0..row0+3] = acc[mt][nt][0..3]  (contiguous -> dwordx4)
    if (bi != bj) {
#pragma unroll
        for (int mt = 0; mt < 4; mt++) {
            const int tcol0 = rbase + mt * 16 + kq * 4;
            if (tcol0 < NN) {  // NN%4==0: all 4 cols valid iff tcol0 < NN
#pragma unroll
                for (int nt = 0; nt < 4; nt++) {
                    const int trow = cbase + nt * 16 + m16;
                    if (trow < NN)
                        *(f32x4*)&C[(size_t)trow * NN + tcol0] = acc[mt][nt];
                }
            }
        }
    }
}

// ---------------------------------------------------------------------------
extern "C" void kernel_launch(void* const* d_in, const int* in_sizes, int n_in,
                              void* d_out, int out_size, void* d_ws, size_t ws_size,
                              hipStream_t stream) {
    const float* z = (const float*)d_in[0];
    const int* ei = (const int*)d_in[1];  // [2, E]: row=ei[0:E], col=ei[E:2E]
    const float* W = (const float*)d_in[2];
    const float* b = (const float*)d_in[3];
    float* C = (float*)d_out;

    char* ws = (char*)d_ws;
    int* cnt = (int*)(ws + OFF_CNT);
    int* fill = (int*)(ws + OFF_FILL);
    int* rowptr = (int*)(ws + OFF_ROWPTR);
    int* srcrow = (int*)(ws + OFF_SRC);
    float* dinv = (float*)(ws + OFF_DINV);
    float* h = (float*)(ws + OFF_H);
    __bf16* zr1 = (__bf16*)(ws + OFF_ZR1);
    __bf16* zr2 = (__bf16*)(ws + OFF_ZR2);

    init_kernel<<<(NN + 255) / 256, 256, 0, stream>>>(cnt, fill,
                                                      (unsigned short*)zr1,
                                                      (unsigned short*)zr2);
    count_kernel<<<(NE + 255) / 256, 256, 0, stream>>>(ei, cnt);
    dinv_kernel<<<(NN + 255) / 256, 256, 0, stream>>>(cnt, dinv);
    scan_kernel<<<1, 256, 0, stream>>>(cnt, rowptr);
    fill_kernel<<<(NE + 255) / 256, 256, 0, stream>>>(ei, rowptr, fill, srcrow);
    h_kernel<<<NN / 4, 256, 0, stream>>>(z, W, h);
    agg_kernel<<<(NN + 3) / 4, 256, 0, stream>>>(rowptr, srcrow, dinv, h, b, zr1, zr2);

    gemm_kernel<<<NPAIRS, 256, 0, stream>>>(zr1, zr2, C);
}